// Round 5
// baseline (309.274 us; speedup 1.0000x reference)
//
#include <hip/hip_runtime.h>
#include <hip/hip_bf16.h>
#include <stdint.h>

// MutualCrossAttention: B=8, C=64, H=W=64 -> T=4096 tokens. Inputs FP32, output FP32.
// dir A: Q=x1, K=V=x2 ; dir B: Q=x2, K=V=x1 ; out = outA + outB, layout [b][c][t].
// R17: kill the ktile K-staging entirely (it was 60% of the LDS-port cost: wrst
// writes + kf b128 reads = 144 of 240 LDS-cyc per iter-wave, plus both barriers
// existed only to protect it). K frags now load DIRECTLY from token-major xt into
// NAMED registers, double-buffered one full phase ahead (kA set / kB set), so the
// ~300cy L2 latency is covered by S+PV of the interleaving phase. V stays as the
// R16 named-reg prefetch (single set, WAR-safe reuse after PV consumes it).
// R13 tried global-K and lost 1.7x; the three causes are each fixed here:
//   (a) prefetch depth was ~1/4 iter -> now a full phase, ping-pong K sets;
//   (b) VGPR cap 64 forced scratch spill -> __launch_bounds__(512,2) (R16-proved);
//   (c) free-running waves lost pair-wave L1 dedupe -> keep ONE pacing barrier
//       per j so pair-waves issue identical K/V addresses in the same epoch.
// LDS = pbuf + lpx only (~38 KB). 32 barriers (was 64). R16 proved occupancy
// is NOT the limiter (22% vs 44% at equal perf), so 1 blk/CU at ~160 VGPR is fine.
//   - S^T composition (A=K,B=Q then A=V,B=P^T) proved in R3-R5; P^T C/D layout
//     gives 4 consecutive tokens/lane -> b64 pbuf write, b128 read, stride-72.
//   - lp is one scalar per lane (q = l16 column), butterflied over quads.
//   - O^T epilogue: row=c, col=q -> scalar f32 stores coalesced over l16.
// ws: [0,8MB) xt bf16 token-major {x1,x2} PRE-SCALED by sqrt(log2(e)/8);
//     [8MB,16MB) vt bf16 c-major {x1,x2} unscaled.

#define TT 4096
#define CC 64
#define NB 8

typedef float f32x4 __attribute__((ext_vector_type(4)));
typedef float f32x4a __attribute__((ext_vector_type(4), may_alias));
typedef short s16x8 __attribute__((ext_vector_type(8)));
typedef unsigned int u32x2a __attribute__((ext_vector_type(2), may_alias));
typedef unsigned int u32x4a __attribute__((ext_vector_type(4), may_alias));
typedef float f32a __attribute__((may_alias));

static __device__ __forceinline__ unsigned fbits(float x) { return __float_as_uint(x); }
static __device__ __forceinline__ ushort bf16of(float v) {
    return (ushort)((fbits(v) + 0x8000u) >> 16);
}
static __device__ __forceinline__ unsigned pack2(float a, float b) {
    return __builtin_amdgcn_perm(fbits(b) + 0x8000u, fbits(a) + 0x8000u, 0x07060302u);
}
static __device__ __forceinline__ s16x8 load_frag(const void* p) {
    u32x4a t = *(const u32x4a*)p;
    return __builtin_bit_cast(s16x8, t);
}

#define SQC1 0.4246609177f  // sqrt(log2(e)/8), applied to xt on both Q and K sides

__global__ void prep_k(const float* __restrict__ x1, const float* __restrict__ x2,
                       ushort* __restrict__ xt, ushort* __restrict__ vt) {
    const int inp = blockIdx.z, b = blockIdx.y, t0 = blockIdx.x * 64;
    const float* src = (inp == 0 ? x1 : x2) + (size_t)b * CC * TT;
    const size_t plane = (size_t)TT * CC;
    ushort* xd = xt + (size_t)(inp * NB + b) * plane;
    ushort* vd = vt + (size_t)(inp * NB + b) * plane;
    __shared__ ushort lds[64][72];
    const int tid = threadIdx.x;
    const int c  = tid >> 2;
    const int tg = tid & 3;
    const float* srow = src + (size_t)c * TT + t0 + tg * 16;
    unsigned hw[8];
#pragma unroll
    for (int i = 0; i < 4; ++i) {
        f32x4a v = *(const f32x4a*)(srow + i * 4);
        hw[2 * i]     = pack2(v[0], v[1]);
        hw[2 * i + 1] = pack2(v[2], v[3]);
#pragma unroll
        for (int k = 0; k < 4; ++k) lds[tg * 16 + i * 4 + k][c] = bf16of(v[k] * SQC1);
    }
    ushort* vrow = vd + (size_t)c * TT + t0 + tg * 16;
    u32x4a w0 = {hw[0], hw[1], hw[2], hw[3]};
    u32x4a w1 = {hw[4], hw[5], hw[6], hw[7]};
    *(u32x4a*)(vrow) = w0;
    *(u32x4a*)(vrow + 8) = w1;
    __syncthreads();
#pragma unroll
    for (int pass = 0; pass < 2; ++pass) {
        const int t  = (tid >> 3) + pass * 32;
        const int c8 = (tid & 7) * 8;
        u32x4a w = *(const u32x4a*)&lds[t][c8];
        *(u32x4a*)(xd + (size_t)(t0 + t) * CC + c8) = w;
    }
}

// grid = 512 blocks (qt 0..63 x b 0..7), 512 threads = 8 waves.
// wave: dir = w&1, pair = (w>>1)&1, ks = w>>2 (2048-token half).
__global__ __launch_bounds__(512, 2)
void attn_fused_k(const ushort* __restrict__ xt, const ushort* __restrict__ vt,
                  float* __restrict__ out) {
    const int b    = blockIdx.x & 7;
    const int qt   = blockIdx.x >> 3;
    const int tid  = threadIdx.x;
    const int wave = tid >> 6;
    const int lane = tid & 63;
    const int quad = lane >> 4;
    const int l16  = lane & 15;
    const int dir  = wave & 1;
    const int pair = (wave >> 1) & 1;
    const int ks   = wave >> 2;
    const int q0   = qt * 64 + pair * 32;

    const size_t plane = (size_t)TT * CC;
    const ushort* Qb = xt + (size_t)((dir == 0 ? 0 : NB) + b) * plane;  // token-major
    const ushort* Kb = xt + (size_t)((dir == 0 ? NB : 0) + b) * plane;  // token-major
    const ushort* Vb = vt + (size_t)((dir == 0 ? NB : 0) + b) * plane;  // c-major

    __shared__ __align__(16) ushort pbuf[8][2][16][72];    // 36.9 KB (q rows, tok cols)
    __shared__ float lpx[8][2][16];                        // 1 KB
    f32a* xbuf = (f32a*)&pbuf[0][0][0][0];                 // 16 KB overlay, post-loop

    // Q b-frags: B[n=q=l16][k=c=quad*8+j], pre-scaled.
    s16x8 qf[2][2];
#pragma unroll
    for (int rb = 0; rb < 2; ++rb)
#pragma unroll
        for (int ch = 0; ch < 2; ++ch)
            qf[rb][ch] = load_frag(Qb + (size_t)(q0 + rb * 16 + l16) * CC + ch * 32 + quad * 8);

    f32x4 accO[2][4];  // O^T partial: row=c=quad*4+r (+ct*16), col=q=l16 (+rb*16)
#pragma unroll
    for (int rb = 0; rb < 2; ++rb)
#pragma unroll
        for (int ct = 0; ct < 4; ++ct) accO[rb][ct] = (f32x4){0.f, 0.f, 0.f, 0.f};
    float lp[2] = {0.f, 0.f};

    // Direct-global K frags: A[m=tok=mt*16+l16][k=c=quad*8..], token-major row.
    const ushort* kbase = Kb + (size_t)(ks * 2048 + l16) * CC + quad * 8;
    const ushort* vbase = Vb + (size_t)l16 * TT + ks * 2048 + quad * 8;

    // Named registers only (R14/R15 lesson: arrays spill under pressure).
    s16x8 kA0, kA1, kA2, kA3, kA4, kA5, kA6, kA7;   // K set A: (mt,ch) pairs
    s16x8 kB0, kB1, kB2, kB3, kB4, kB5, kB6, kB7;   // K set B
    s16x8 v0, v1, v2, v3, v4, v5, v6, v7;           // V: ct 0..3 x ch2 0/1

    auto loadKA = [&](int j) {
        const ushort* p = kbase + (size_t)j * 64 * CC;
        kA0 = load_frag(p);               kA1 = load_frag(p + 32);
        kA2 = load_frag(p + 16 * CC);     kA3 = load_frag(p + 16 * CC + 32);
        kA4 = load_frag(p + 32 * CC);     kA5 = load_frag(p + 32 * CC + 32);
        kA6 = load_frag(p + 48 * CC);     kA7 = load_frag(p + 48 * CC + 32);
    };
    auto loadKB = [&](int j) {
        const ushort* p = kbase + (size_t)j * 64 * CC;
        kB0 = load_frag(p);               kB1 = load_frag(p + 32);
        kB2 = load_frag(p + 16 * CC);     kB3 = load_frag(p + 16 * CC + 32);
        kB4 = load_frag(p + 32 * CC);     kB5 = load_frag(p + 32 * CC + 32);
        kB6 = load_frag(p + 48 * CC);     kB7 = load_frag(p + 48 * CC + 32);
    };
    auto loadV = [&](int j) {
        const ushort* p = vbase + (size_t)j * 64;
        v0 = load_frag(p);                     v4 = load_frag(p + 32);
        v1 = load_frag(p + (size_t)16 * TT);   v5 = load_frag(p + (size_t)16 * TT + 32);
        v2 = load_frag(p + (size_t)32 * TT);   v6 = load_frag(p + (size_t)32 * TT + 32);
        v3 = load_frag(p + (size_t)48 * TT);   v7 = load_frag(p + (size_t)48 * TT + 32);
    };

    // One mt-slice of S^T: D[row=tok=quad*4+r (+mt*16)][col=q=l16] -> b64 P write.
    auto SmT = [&](s16x8 kc0, s16x8 kc1, int mt) {
#pragma unroll
        for (int rb = 0; rb < 2; ++rb) {
            f32x4 s = (f32x4){0.f, 0.f, 0.f, 0.f};
            s = __builtin_amdgcn_mfma_f32_16x16x32_bf16(kc0, qf[rb][0], s, 0, 0, 0);
            s = __builtin_amdgcn_mfma_f32_16x16x32_bf16(kc1, qf[rb][1], s, 0, 0, 0);
            float p0 = __builtin_amdgcn_exp2f(s[0]);
            float p1 = __builtin_amdgcn_exp2f(s[1]);
            float p2 = __builtin_amdgcn_exp2f(s[2]);
            float p3 = __builtin_amdgcn_exp2f(s[3]);
            lp[rb] += (p0 + p1) + (p2 + p3);
            u32x2a w;
            w[0] = pack2(p0, p1);
            w[1] = pack2(p2, p3);
            *(u32x2a*)&pbuf[wave][rb][l16][mt * 16 + quad * 4] = w;
        }
    };
    // PV(j): A = V (prefetched named regs) [m=c=l16(+ct*16)][k=tok],
    //        B = P^T [n=q=l16][k=tok] (b128 LDS read). Pure reg-MFMA otherwise.
    auto PVphase = [&]() {
        s16x8 pf0a = load_frag(&pbuf[wave][0][l16][quad * 8]);
        s16x8 pf1a = load_frag(&pbuf[wave][1][l16][quad * 8]);
        accO[0][0] = __builtin_amdgcn_mfma_f32_16x16x32_bf16(v0, pf0a, accO[0][0], 0, 0, 0);
        accO[1][0] = __builtin_amdgcn_mfma_f32_16x16x32_bf16(v0, pf1a, accO[1][0], 0, 0, 0);
        accO[0][1] = __builtin_amdgcn_mfma_f32_16x16x32_bf16(v1, pf0a, accO[0][1], 0, 0, 0);
        accO[1][1] = __builtin_amdgcn_mfma_f32_16x16x32_bf16(v1, pf1a, accO[1][1], 0, 0, 0);
        accO[0][2] = __builtin_amdgcn_mfma_f32_16x16x32_bf16(v2, pf0a, accO[0][2], 0, 0, 0);
        accO[1][2] = __builtin_amdgcn_mfma_f32_16x16x32_bf16(v2, pf1a, accO[1][2], 0, 0, 0);
        accO[0][3] = __builtin_amdgcn_mfma_f32_16x16x32_bf16(v3, pf0a, accO[0][3], 0, 0, 0);
        accO[1][3] = __builtin_amdgcn_mfma_f32_16x16x32_bf16(v3, pf1a, accO[1][3], 0, 0, 0);
        s16x8 pf0b = load_frag(&pbuf[wave][0][l16][32 + quad * 8]);
        s16x8 pf1b = load_frag(&pbuf[wave][1][l16][32 + quad * 8]);
        accO[0][0] = __builtin_amdgcn_mfma_f32_16x16x32_bf16(v4, pf0b, accO[0][0], 0, 0, 0);
        accO[1][0] = __builtin_amdgcn_mfma_f32_16x16x32_bf16(v4, pf1b, accO[1][0], 0, 0, 0);
        accO[0][1] = __builtin_amdgcn_mfma_f32_16x16x32_bf16(v5, pf0b, accO[0][1], 0, 0, 0);
        accO[1][1] = __builtin_amdgcn_mfma_f32_16x16x32_bf16(v5, pf1b, accO[1][1], 0, 0, 0);
        accO[0][2] = __builtin_amdgcn_mfma_f32_16x16x32_bf16(v6, pf0b, accO[0][2], 0, 0, 0);
        accO[1][2] = __builtin_amdgcn_mfma_f32_16x16x32_bf16(v6, pf1b, accO[1][2], 0, 0, 0);
        accO[0][3] = __builtin_amdgcn_mfma_f32_16x16x32_bf16(v7, pf0b, accO[0][3], 0, 0, 0);
        accO[1][3] = __builtin_amdgcn_mfma_f32_16x16x32_bf16(v7, pf1b, accO[1][3], 0, 0, 0);
    };

    // Ping-pong pipeline, unroll 2. Per j: [pacing bar] -> issue next K set ->
    // S(j) (waits only the OLDER K set via counted vmcnt) -> PV(j) -> issue V(j+1)
    // (WAR-safe: PV already consumed v*). Each prefetch gets a full S+PV of cover.
    loadKA(0);
    loadV(0);
#pragma unroll 1
    for (int j = 0; j < 32; j += 2) {
        __syncthreads();                 // pacing: keep pair-waves L1-coherent
        loadKB(j + 1);
        SmT(kA0, kA1, 0); SmT(kA2, kA3, 1); SmT(kA4, kA5, 2); SmT(kA6, kA7, 3);
        PVphase();                       // PV(j)
        loadV(j + 1);
        __syncthreads();
        if (j + 2 < 32) loadKA(j + 2);
        SmT(kB0, kB1, 0); SmT(kB2, kB3, 1); SmT(kB4, kB5, 2); SmT(kB6, kB7, 3);
        PVphase();                       // PV(j+1)
        if (j + 2 < 32) loadV(j + 2);
    }

    // Denominator: quads hold disjoint token subsets for col q=l16.
    float inv[2];
#pragma unroll
    for (int rb = 0; rb < 2; ++rb) {
        float l = lp[rb];
        l += __shfl_xor(l, 16);
        l += __shfl_xor(l, 32);
        lp[rb] = l;
        if (lane < 16) lpx[wave][rb][l16] = l;
    }
    __syncthreads();  // all waves done with pbuf -> xbuf overlay safe; lpx visible
#pragma unroll
    for (int rb = 0; rb < 2; ++rb)
        inv[rb] = __builtin_amdgcn_rcpf(lp[rb] + lpx[wave ^ 4][rb][l16]);

    // 4-phase merge over g = (ks,dir) into xbuf[pair]; g==0 stores.
    const int g = (ks << 1) | dir;
#pragma unroll 1
    for (int ph = 3; ph >= 1; --ph) {
        if (g == ph) {
#pragma unroll
            for (int rb = 0; rb < 2; ++rb)
#pragma unroll
                for (int ct = 0; ct < 4; ++ct)
#pragma unroll
                    for (int r = 0; r < 4; ++r) {
                        const int slot = (pair * 32 + rb * 16 + ct * 4 + r) * 64 + lane;
                        float v = accO[rb][ct][r] * inv[rb];
                        if (ph == 3) xbuf[slot] = v;
                        else xbuf[slot] += v;
                    }
        }
        __syncthreads();
    }
    if (g == 0) {
        float* ob = out + (size_t)b * plane;
#pragma unroll
        for (int rb = 0; rb < 2; ++rb)
#pragma unroll
            for (int ct = 0; ct < 4; ++ct)
#pragma unroll
                for (int r = 0; r < 4; ++r) {
                    float v = accO[rb][ct][r] * inv[rb] +
                              xbuf[(pair * 32 + rb * 16 + ct * 4 + r) * 64 + lane];
                    // out[c = ct*16+quad*4+r][t = q0+rb*16+l16]: coalesced over l16
                    ob[(size_t)(ct * 16 + quad * 4 + r) * TT + q0 + rb * 16 + l16] = v;
                }
    }
}

extern "C" void kernel_launch(void* const* d_in, const int* in_sizes, int n_in,
                              void* d_out, int out_size, void* d_ws, size_t ws_size,
                              hipStream_t stream) {
    const float* x1 = (const float*)d_in[0];
    const float* x2 = (const float*)d_in[1];
    ushort* xt = (ushort*)d_ws;                              // 8 MB
    ushort* vt = (ushort*)d_ws + (size_t)2 * NB * TT * CC;   // 8 MB

    hipLaunchKernelGGL(prep_k, dim3(TT / 64, NB, 2), dim3(256), 0, stream, x1, x2, xt, vt);
    hipLaunchKernelGGL(attn_fused_k, dim3(64 * NB), dim3(512), 0, stream,
                       xt, vt, (float*)d_out);
}

// Round 6
// 172.991 us; speedup vs baseline: 1.7878x; 1.7878x over previous
//
#include <hip/hip_runtime.h>
#include <hip/hip_bf16.h>
#include <stdint.h>

// MutualCrossAttention: B=8, C=64, H=W=64 -> T=4096 tokens. Inputs FP32, output FP32.
// dir A: Q=x1, K=V=x2 ; dir B: Q=x2, K=V=x1 ; out = outA + outB, layout [b][c][t].
// R18 = R17 structure (no ktile, no staging, 1 pacing barrier/j, named-reg K
// ping-pong + V prefetch, __launch_bounds__(512,2)) with K/V/Q PRE-PACKED INTO
// MFMA FRAGMENT ORDER by prep_k. Diagnosis chain: R12(168,K-LDS) vs R17(253,
// K-global, latency-covered, spill-free) proves per-lane fragment loads from
// global are TRANSACTION-AMPLIFIED (~16 cache lines per instruction at 128B/8KB
// lane stride) — the V loads had this tax since R12. Packed layout makes every
// hot-loop load instruction a contiguous 1KB block (lane i at base + i*16B):
//   kt chunk(tt,mt,ch):  lane(quad,l16) holds K[t=tt*64+mt*16+l16][c=ch*32+quad*8+e]
//   vt chunk(tt,ch2,ct): lane(quad,l16) holds V[c=ct*16+l16][t=tt*64+ch2*32+quad*8+e]
// Q frags are kt chunks at (qt, mt=pair*2+rb, ch) -> token-major xt eliminated.
//   - S^T composition (A=K,B=Q then A=V,B=P^T) proved in R3-R5; P^T C/D layout
//     gives 4 consecutive tokens/lane -> b64 pbuf write, b128 read, stride-72.
//   - lp is one scalar per lane (q = l16 column), butterflied over quads.
//   - O^T epilogue: row=c, col=q -> scalar f32 stores coalesced over l16.
// ws: [0,8MB) kt bf16 frag-packed {x1,x2} PRE-SCALED by sqrt(log2(e)/8);
//     [8MB,16MB) vt bf16 frag-packed {x1,x2} unscaled.

#define TT 4096
#define CC 64
#define NB 8

typedef float f32x4 __attribute__((ext_vector_type(4)));
typedef float f32x4a __attribute__((ext_vector_type(4), may_alias));
typedef short s16x8 __attribute__((ext_vector_type(8)));
typedef unsigned int u32x2a __attribute__((ext_vector_type(2), may_alias));
typedef unsigned int u32x4a __attribute__((ext_vector_type(4), may_alias));
typedef float f32a __attribute__((may_alias));

static __device__ __forceinline__ unsigned fbits(float x) { return __float_as_uint(x); }
static __device__ __forceinline__ ushort bf16of(float v) {
    return (ushort)((fbits(v) + 0x8000u) >> 16);
}
static __device__ __forceinline__ unsigned pack2(float a, float b) {
    return __builtin_amdgcn_perm(fbits(b) + 0x8000u, fbits(a) + 0x8000u, 0x07060302u);
}
static __device__ __forceinline__ s16x8 load_frag(const void* p) {
    u32x4a t = *(const u32x4a*)p;
    return __builtin_bit_cast(s16x8, t);
}

#define SQC1 0.4246609177f  // sqrt(log2(e)/8), applied to kt on both Q and K sides

// grid (TT/64, NB, 2), 256 threads. Reads c-major f32, emits frag-packed bf16.
__global__ void prep_k(const float* __restrict__ x1, const float* __restrict__ x2,
                       ushort* __restrict__ kt, ushort* __restrict__ vt) {
    const int inp = blockIdx.z, b = blockIdx.y, tt = blockIdx.x;
    const float* src = (inp == 0 ? x1 : x2) + (size_t)b * CC * TT;
    const size_t plane = (size_t)TT * CC;
    ushort* kd = kt + (size_t)(inp * NB + b) * plane;
    ushort* vd = vt + (size_t)(inp * NB + b) * plane;
    __shared__ ushort lds[64][72];
    const int tid = threadIdx.x;
    const int c  = tid >> 2;        // 0..63: channel row
    const int tg = tid & 3;         // 16-token group within the 64-token tile
    const float* srow = src + (size_t)c * TT + tt * 64 + tg * 16;
    unsigned hw[8];
#pragma unroll
    for (int i = 0; i < 4; ++i) {
        f32x4a v = *(const f32x4a*)(srow + i * 4);
        hw[2 * i]     = pack2(v[0], v[1]);
        hw[2 * i + 1] = pack2(v[2], v[3]);
#pragma unroll
        for (int k = 0; k < 4; ++k) lds[tg * 16 + i * 4 + k][c] = bf16of(v[k] * SQC1);
    }
    // vt frag-packed (unscaled): thread(c,tg) owns V[c][t_local=tg*16..+16] =
    // chunk(tt, ch2=tg>>1, ct=c>>4), lanes (quad=(tg&1)*2 and +1, l16=c&15).
    {
        ushort* vchunk = vd + (((size_t)tt * 2 + (tg >> 1)) * 4 + (c >> 4)) * 512;
        const int l16v = c & 15;
        const int q0v  = (tg & 1) * 2;
        u32x4a w0 = {hw[0], hw[1], hw[2], hw[3]};
        u32x4a w1 = {hw[4], hw[5], hw[6], hw[7]};
        *(u32x4a*)(vchunk + (size_t)(q0v * 16 + l16v) * 8)       = w0;
        *(u32x4a*)(vchunk + (size_t)((q0v + 1) * 16 + l16v) * 8) = w1;
    }
    __syncthreads();
    // kt frag-packed (scaled, from transposed LDS): tid = mt*64 + quad*16 + l16.
    // chunk(tt, mt, ch): lane holds 8 consecutive c at row t = mt*16 + l16.
    const int mt   = tid >> 6;
    const int quad = (tid >> 4) & 3;
    const int l16  = tid & 15;
    const int t    = mt * 16 + l16;
#pragma unroll
    for (int ch = 0; ch < 2; ++ch) {
        u32x4a w = *(const u32x4a*)&lds[t][ch * 32 + quad * 8];
        *(u32x4a*)(kd + (((size_t)tt * 4 + mt) * 2 + ch) * 512 +
                   (size_t)(quad * 16 + l16) * 8) = w;
    }
}

// grid = 512 blocks (qt 0..63 x b 0..7), 512 threads = 8 waves.
// wave: dir = w&1, pair = (w>>1)&1, ks = w>>2 (2048-token half).
__global__ __launch_bounds__(512, 2)
void attn_fused_k(const ushort* __restrict__ kt, const ushort* __restrict__ vt,
                  float* __restrict__ out) {
    const int b    = blockIdx.x & 7;
    const int qt   = blockIdx.x >> 3;
    const int tid  = threadIdx.x;
    const int wave = tid >> 6;
    const int lane = tid & 63;
    const int quad = lane >> 4;
    const int l16  = lane & 15;
    const int dir  = wave & 1;
    const int pair = (wave >> 1) & 1;
    const int ks   = wave >> 2;
    const int q0   = qt * 64 + pair * 32;

    const size_t plane = (size_t)TT * CC;
    // All hot-loop loads: base + chunk*512 + lane*8 (ushorts) = contiguous 1KB/instr.
    const ushort* Qp = kt + (size_t)((dir == 0 ? 0 : NB) + b) * plane + (size_t)lane * 8;
    const ushort* Kp = kt + (size_t)((dir == 0 ? NB : 0) + b) * plane + (size_t)lane * 8;
    const ushort* Vp = vt + (size_t)((dir == 0 ? NB : 0) + b) * plane + (size_t)lane * 8;

    __shared__ __align__(16) ushort pbuf[8][2][16][72];    // 36.9 KB (q rows, tok cols)
    __shared__ float lpx[8][2][16];                        // 1 KB
    f32a* xbuf = (f32a*)&pbuf[0][0][0][0];                 // 16 KB overlay, post-loop

    // Q b-frags = kt chunks (qt, mt = pair*2 + rb, ch), pre-scaled.
    s16x8 qf[2][2];
#pragma unroll
    for (int rb = 0; rb < 2; ++rb)
#pragma unroll
        for (int ch = 0; ch < 2; ++ch)
            qf[rb][ch] = load_frag(Qp + (((size_t)qt * 4 + pair * 2 + rb) * 2 + ch) * 512);

    f32x4 accO[2][4];  // O^T partial: row=c=quad*4+r (+ct*16), col=q=l16 (+rb*16)
#pragma unroll
    for (int rb = 0; rb < 2; ++rb)
#pragma unroll
        for (int ct = 0; ct < 4; ++ct) accO[rb][ct] = (f32x4){0.f, 0.f, 0.f, 0.f};
    float lp[2] = {0.f, 0.f};

    // Named registers only (R14/R15 lesson: arrays spill under pressure).
    s16x8 kA0, kA1, kA2, kA3, kA4, kA5, kA6, kA7;   // K set A: chunks (mt,ch)
    s16x8 kB0, kB1, kB2, kB3, kB4, kB5, kB6, kB7;   // K set B
    s16x8 v0, v1, v2, v3, v4, v5, v6, v7;           // V: (ch2,ct)

    auto loadKA = [&](int j) {
        const ushort* p = Kp + (size_t)(ks * 32 + j) * 4096;
        kA0 = load_frag(p);          kA1 = load_frag(p + 512);
        kA2 = load_frag(p + 1024);   kA3 = load_frag(p + 1536);
        kA4 = load_frag(p + 2048);   kA5 = load_frag(p + 2560);
        kA6 = load_frag(p + 3072);   kA7 = load_frag(p + 3584);
    };
    auto loadKB = [&](int j) {
        const ushort* p = Kp + (size_t)(ks * 32 + j) * 4096;
        kB0 = load_frag(p);          kB1 = load_frag(p + 512);
        kB2 = load_frag(p + 1024);   kB3 = load_frag(p + 1536);
        kB4 = load_frag(p + 2048);   kB5 = load_frag(p + 2560);
        kB6 = load_frag(p + 3072);   kB7 = load_frag(p + 3584);
    };
    auto loadV = [&](int j) {
        const ushort* p = Vp + (size_t)(ks * 32 + j) * 4096;
        v0 = load_frag(p);           v1 = load_frag(p + 512);
        v2 = load_frag(p + 1024);    v3 = load_frag(p + 1536);
        v4 = load_frag(p + 2048);    v5 = load_frag(p + 2560);
        v6 = load_frag(p + 3072);    v7 = load_frag(p + 3584);
    };

    // One mt-slice of S^T: D[row=tok=quad*4+r (+mt*16)][col=q=l16] -> b64 P write.
    auto SmT = [&](s16x8 kc0, s16x8 kc1, int mt) {
#pragma unroll
        for (int rb = 0; rb < 2; ++rb) {
            f32x4 s = (f32x4){0.f, 0.f, 0.f, 0.f};
            s = __builtin_amdgcn_mfma_f32_16x16x32_bf16(kc0, qf[rb][0], s, 0, 0, 0);
            s = __builtin_amdgcn_mfma_f32_16x16x32_bf16(kc1, qf[rb][1], s, 0, 0, 0);
            float p0 = __builtin_amdgcn_exp2f(s[0]);
            float p1 = __builtin_amdgcn_exp2f(s[1]);
            float p2 = __builtin_amdgcn_exp2f(s[2]);
            float p3 = __builtin_amdgcn_exp2f(s[3]);
            lp[rb] += (p0 + p1) + (p2 + p3);
            u32x2a w;
            w[0] = pack2(p0, p1);
            w[1] = pack2(p2, p3);
            *(u32x2a*)&pbuf[wave][rb][l16][mt * 16 + quad * 4] = w;
        }
    };
    // PV(j): A = V (prefetched named regs) [m=c=l16(+ct*16)][k=tok],
    //        B = P^T [n=q=l16][k=tok] (b128 LDS read). Pure reg-MFMA otherwise.
    auto PVphase = [&]() {
        s16x8 pf0a = load_frag(&pbuf[wave][0][l16][quad * 8]);
        s16x8 pf1a = load_frag(&pbuf[wave][1][l16][quad * 8]);
        accO[0][0] = __builtin_amdgcn_mfma_f32_16x16x32_bf16(v0, pf0a, accO[0][0], 0, 0, 0);
        accO[1][0] = __builtin_amdgcn_mfma_f32_16x16x32_bf16(v0, pf1a, accO[1][0], 0, 0, 0);
        accO[0][1] = __builtin_amdgcn_mfma_f32_16x16x32_bf16(v1, pf0a, accO[0][1], 0, 0, 0);
        accO[1][1] = __builtin_amdgcn_mfma_f32_16x16x32_bf16(v1, pf1a, accO[1][1], 0, 0, 0);
        accO[0][2] = __builtin_amdgcn_mfma_f32_16x16x32_bf16(v2, pf0a, accO[0][2], 0, 0, 0);
        accO[1][2] = __builtin_amdgcn_mfma_f32_16x16x32_bf16(v2, pf1a, accO[1][2], 0, 0, 0);
        accO[0][3] = __builtin_amdgcn_mfma_f32_16x16x32_bf16(v3, pf0a, accO[0][3], 0, 0, 0);
        accO[1][3] = __builtin_amdgcn_mfma_f32_16x16x32_bf16(v3, pf1a, accO[1][3], 0, 0, 0);
        s16x8 pf0b = load_frag(&pbuf[wave][0][l16][32 + quad * 8]);
        s16x8 pf1b = load_frag(&pbuf[wave][1][l16][32 + quad * 8]);
        accO[0][0] = __builtin_amdgcn_mfma_f32_16x16x32_bf16(v4, pf0b, accO[0][0], 0, 0, 0);
        accO[1][0] = __builtin_amdgcn_mfma_f32_16x16x32_bf16(v4, pf1b, accO[1][0], 0, 0, 0);
        accO[0][1] = __builtin_amdgcn_mfma_f32_16x16x32_bf16(v5, pf0b, accO[0][1], 0, 0, 0);
        accO[1][1] = __builtin_amdgcn_mfma_f32_16x16x32_bf16(v5, pf1b, accO[1][1], 0, 0, 0);
        accO[0][2] = __builtin_amdgcn_mfma_f32_16x16x32_bf16(v6, pf0b, accO[0][2], 0, 0, 0);
        accO[1][2] = __builtin_amdgcn_mfma_f32_16x16x32_bf16(v6, pf1b, accO[1][2], 0, 0, 0);
        accO[0][3] = __builtin_amdgcn_mfma_f32_16x16x32_bf16(v7, pf0b, accO[0][3], 0, 0, 0);
        accO[1][3] = __builtin_amdgcn_mfma_f32_16x16x32_bf16(v7, pf1b, accO[1][3], 0, 0, 0);
    };

    // Ping-pong pipeline, unroll 2. Per j: [pacing bar] -> issue next K set ->
    // S(j) (waits only the OLDER K set via counted vmcnt) -> PV(j) -> issue V(j+1)
    // (WAR-safe: PV already consumed v*). Each prefetch gets a full S+PV of cover.
    loadKA(0);
    loadV(0);
#pragma unroll 1
    for (int j = 0; j < 32; j += 2) {
        __syncthreads();                 // pacing: keep pair-waves L1-coherent
        loadKB(j + 1);
        SmT(kA0, kA1, 0); SmT(kA2, kA3, 1); SmT(kA4, kA5, 2); SmT(kA6, kA7, 3);
        PVphase();                       // PV(j)
        loadV(j + 1);
        __syncthreads();
        if (j + 2 < 32) loadKA(j + 2);
        SmT(kB0, kB1, 0); SmT(kB2, kB3, 1); SmT(kB4, kB5, 2); SmT(kB6, kB7, 3);
        PVphase();                       // PV(j+1)
        if (j + 2 < 32) loadV(j + 2);
    }

    // Denominator: quads hold disjoint token subsets for col q=l16.
    float inv[2];
#pragma unroll
    for (int rb = 0; rb < 2; ++rb) {
        float l = lp[rb];
        l += __shfl_xor(l, 16);
        l += __shfl_xor(l, 32);
        lp[rb] = l;
        if (lane < 16) lpx[wave][rb][l16] = l;
    }
    __syncthreads();  // all waves done with pbuf -> xbuf overlay safe; lpx visible
#pragma unroll
    for (int rb = 0; rb < 2; ++rb)
        inv[rb] = __builtin_amdgcn_rcpf(lp[rb] + lpx[wave ^ 4][rb][l16]);

    // 4-phase merge over g = (ks,dir) into xbuf[pair]; g==0 stores.
    const int g = (ks << 1) | dir;
#pragma unroll 1
    for (int ph = 3; ph >= 1; --ph) {
        if (g == ph) {
#pragma unroll
            for (int rb = 0; rb < 2; ++rb)
#pragma unroll
                for (int ct = 0; ct < 4; ++ct)
#pragma unroll
                    for (int r = 0; r < 4; ++r) {
                        const int slot = (pair * 32 + rb * 16 + ct * 4 + r) * 64 + lane;
                        float v = accO[rb][ct][r] * inv[rb];
                        if (ph == 3) xbuf[slot] = v;
                        else xbuf[slot] += v;
                    }
        }
        __syncthreads();
    }
    if (g == 0) {
        float* ob = out + (size_t)b * plane;
#pragma unroll
        for (int rb = 0; rb < 2; ++rb)
#pragma unroll
            for (int ct = 0; ct < 4; ++ct)
#pragma unroll
                for (int r = 0; r < 4; ++r) {
                    float v = accO[rb][ct][r] * inv[rb] +
                              xbuf[(pair * 32 + rb * 16 + ct * 4 + r) * 64 + lane];
                    // out[c = ct*16+quad*4+r][t = q0+rb*16+l16]: coalesced over l16
                    ob[(size_t)(ct * 16 + quad * 4 + r) * TT + q0 + rb * 16 + l16] = v;
                }
    }
}

extern "C" void kernel_launch(void* const* d_in, const int* in_sizes, int n_in,
                              void* d_out, int out_size, void* d_ws, size_t ws_size,
                              hipStream_t stream) {
    const float* x1 = (const float*)d_in[0];
    const float* x2 = (const float*)d_in[1];
    ushort* kt = (ushort*)d_ws;                              // 8 MB frag-packed K/Q
    ushort* vt = (ushort*)d_ws + (size_t)2 * NB * TT * CC;   // 8 MB frag-packed V

    hipLaunchKernelGGL(prep_k, dim3(TT / 64, NB, 2), dim3(256), 0, stream, x1, x2, kt, vt);
    hipLaunchKernelGGL(attn_fused_k, dim3(64 * NB), dim3(512), 0, stream,
                       kt, vt, (float*)d_out);
}